// Round 3
// baseline (720.738 us; speedup 1.0000x reference)
//
#include <hip/hip_runtime.h>
#include <hip/hip_bf16.h>

typedef __hip_bfloat16 bf16;
typedef __attribute__((ext_vector_type(8))) __bf16 bf16x8;
typedef __attribute__((ext_vector_type(4))) float f32x4;

#define BM 128
#define BN 128

typedef const __attribute__((address_space(1))) void gvoid;
typedef __attribute__((address_space(3))) void lvoid;

// NT GEMM: C[m,n] = sum_k A[m,k] * B[n,k]   (both row-major, K contiguous)
// z decomposes as zb = z>>3 (local batch), zh = z&7 (head).
// SLICEX: slice index lives in blockIdx.x (XCD-pinned: zh == XCD id), n-tile in blockIdx.z.
// MODE 0: C bf16 = acc + bias[zh*sBiasZ + m]                 (v proj)
// MODE 1: C bf16 = acc + bias[n]                             (qk proj)
// MODE 3: C bf16 = gamma[zh]*acc + xt[zb*1M + m*ldxt + n]    (o -> heads_t)
// MODE 4: C bf16 = relu(acc + bias[n])                       (fc1)
// MODE 5: out f32 scatter + residual (m local row; Cv/xf pre-offset per pass)
template<int MODE, int TBK, bool SLICEX>
__global__ __launch_bounds__(256)
void gemm_nt(const bf16* __restrict__ A, long lda, long sAb, long sAh,
             const bf16* __restrict__ B, long ldb, long sBb, long sBh,
             void* __restrict__ Cv, long ldc, long sCb, long sCh,
             int K,
             const float* __restrict__ bias, long sBiasZ,
             const float* __restrict__ gamma,
             const bf16* __restrict__ xt, long ldxt,
             const float* __restrict__ xf)
{
    __shared__ bf16 As[BM * TBK];
    __shared__ bf16 Bs[BN * TBK];
    const int bxt = SLICEX ? blockIdx.z : blockIdx.x;   // n-tile
    const int z   = SLICEX ? blockIdx.x : blockIdx.z;   // slice
    const int zb = z >> 3, zh = z & 7;
    const bf16* Ab = A + (long)zb * sAb + (long)zh * sAh + (long)blockIdx.y * BM * lda;
    const bf16* Bb = B + (long)zb * sBb + (long)zh * sBh + (long)bxt * BN * ldb;
    const int tid  = threadIdx.x;
    const int wave = tid >> 6, lane = tid & 63;
    const int col  = lane & 15, quad = lane >> 4;
    const int wm = (wave & 1) * 64, wn = (wave >> 1) * 64;
    constexpr int CPR = TBK / 8;            // 16B chunks per row

    f32x4 acc[4][4] = {};

    for (int k0 = 0; k0 < K; k0 += TBK) {
        __syncthreads();
        #pragma unroll
        for (int i = 0; i < TBK / 16; ++i) {
            int cbase = i * 256 + wave * 64;     // wave-uniform chunk base
            int c = cbase + lane;                // chunk id
            int m = c / CPR;                     // tile row
            int j = c % CPR;                     // chunk slot in row
            int kch = ((j ^ (m & 7)) << 3);      // swizzled k offset (elements)
            __builtin_amdgcn_global_load_lds(
                (gvoid*)(Ab + (long)m * lda + k0 + kch),
                (lvoid*)(As + cbase * 8), 16, 0, 0);
            __builtin_amdgcn_global_load_lds(
                (gvoid*)(Bb + (long)m * ldb + k0 + kch),
                (lvoid*)(Bs + cbase * 8), 16, 0, 0);
        }
        __syncthreads();
        #pragma unroll
        for (int kk = 0; kk < TBK; kk += 32) {
            bf16x8 af[4], bfr[4];
            int kq = (kk >> 3) + quad;
            #pragma unroll
            for (int mi = 0; mi < 4; ++mi) {
                int m = wm + mi * 16 + col;
                af[mi] = *(const bf16x8*)(As + m * TBK + ((kq ^ (m & 7)) << 3));
            }
            #pragma unroll
            for (int ni = 0; ni < 4; ++ni) {
                int n = wn + ni * 16 + col;
                bfr[ni] = *(const bf16x8*)(Bs + n * TBK + ((kq ^ (n & 7)) << 3));
            }
            #pragma unroll
            for (int mi = 0; mi < 4; ++mi)
                #pragma unroll
                for (int ni = 0; ni < 4; ++ni)
                    acc[mi][ni] = __builtin_amdgcn_mfma_f32_16x16x32_bf16(
                        af[mi], bfr[ni], acc[mi][ni], 0, 0, 0);
        }
    }

    const long m0 = (long)blockIdx.y * BM + wm;
    const long n0 = (long)bxt * BN + wn;
    float g = 0.f;
    if (MODE == 3) g = gamma[zh];
    #pragma unroll
    for (int mi = 0; mi < 4; ++mi) {
        #pragma unroll
        for (int ni = 0; ni < 4; ++ni) {
            long mb = m0 + mi * 16 + quad * 4;
            long n  = n0 + ni * 16 + col;
            #pragma unroll
            for (int r = 0; r < 4; ++r) {
                long m = mb + r;
                float v = acc[mi][ni][r];
                if constexpr (MODE == 0) {
                    v += bias[zh * sBiasZ + m];
                    ((bf16*)Cv)[(long)zb * sCb + (long)zh * sCh + m * ldc + n] = __float2bfloat16(v);
                } else if constexpr (MODE == 1) {
                    v += bias[n];
                    ((bf16*)Cv)[m * ldc + n] = __float2bfloat16(v);
                } else if constexpr (MODE == 3) {
                    float xv = __bfloat162float(xt[(long)zb * 1048576 + m * ldxt + n]);
                    ((bf16*)Cv)[(long)zb * sCb + (long)zh * sCh + m * ldc + n] = __float2bfloat16(g * v + xv);
                } else if constexpr (MODE == 4) {
                    v += bias[n];
                    v = v > 0.f ? v : 0.f;
                    ((bf16*)Cv)[m * ldc + n] = __float2bfloat16(v);
                } else {  // MODE 5: m local = bb*8192 + h*1024 + t (bb within pass)
                    v += bias[n];
                    v = v > 0.f ? v : 0.f;
                    long bb = m >> 13, h = (m >> 10) & 7, t = m & 1023;
                    long oi = bb * 1048576 + (n * 8 + h) * 1024 + t;
                    ((float*)Cv)[oi] = v + xf[oi];
                }
            }
        }
    }
}

// Fused energy + softmax. Grid: (slices, T/32). Block 256 (4 waves).
__global__ __launch_bounds__(256, 2)
void attn_fused(const bf16* __restrict__ qk, bf16* __restrict__ attn)
{
    constexpr int PAD = 1032;
    __shared__ __align__(16) char smraw[40960];   // phase A: Q 8K + K 32K; phase B: Sbuf 33024B
    __shared__ float red[2][4][32];
    bf16* Qs = (bf16*)smraw;                  // [32][128]
    bf16* Ks = (bf16*)(smraw + 8192);         // [128][128]
    bf16* Sbuf = (bf16*)smraw;                // [16][PAD]

    const int z = blockIdx.x;
    const int zb = z >> 3, zh = z & 7;
    const int t0 = blockIdx.y * 32;
    const int tid = threadIdx.x, w = tid >> 6, lane = tid & 63;
    const int col = lane & 15, quad = lane >> 4;

    const bf16* Qbase = qk + ((long)zb * 1024 + t0) * 2048 + zh * 256;
    const bf16* Kbase = qk + (long)zb * 1024 * 2048 + zh * 256 + 128;

    #pragma unroll
    for (int i = 0; i < 2; ++i) {
        int cbase = i * 256 + w * 64;
        int c = cbase + lane;
        int m = c >> 4, j = c & 15;
        __builtin_amdgcn_global_load_lds(
            (gvoid*)(Qbase + (long)m * 2048 + ((j ^ (m & 7)) << 3)),
            (lvoid*)(Qs + cbase * 8), 16, 0, 0);
    }
    __syncthreads();
    bf16x8 af[2][4];
    #pragma unroll
    for (int mi = 0; mi < 2; ++mi) {
        int m = mi * 16 + col;
        #pragma unroll
        for (int ki = 0; ki < 4; ++ki)
            af[mi][ki] = *(const bf16x8*)(Qs + m * 128 + ((((ki << 2) + quad) ^ (m & 7)) << 3));
    }

    f32x4 acc[2][16] = {};
    #pragma unroll
    for (int si = 0; si < 8; ++si) {
        __syncthreads();
        const bf16* Kb = Kbase + (long)si * 128 * 2048;
        #pragma unroll
        for (int i = 0; i < 8; ++i) {
            int cbase = i * 256 + w * 64;
            int c = cbase + lane;
            int m = c >> 4, j = c & 15;
            __builtin_amdgcn_global_load_lds(
                (gvoid*)(Kb + (long)m * 2048 + ((j ^ (m & 7)) << 3)),
                (lvoid*)(Ks + cbase * 8), 16, 0, 0);
        }
        __syncthreads();
        bf16x8 bfr[2][4];
        #pragma unroll
        for (int ni = 0; ni < 2; ++ni) {
            int n = w * 32 + ni * 16 + col;
            #pragma unroll
            for (int ki = 0; ki < 4; ++ki)
                bfr[ni][ki] = *(const bf16x8*)(Ks + n * 128 + ((((ki << 2) + quad) ^ (n & 7)) << 3));
        }
        #pragma unroll
        for (int ki = 0; ki < 4; ++ki)
            #pragma unroll
            for (int mi = 0; mi < 2; ++mi)
                #pragma unroll
                for (int ni = 0; ni < 2; ++ni)
                    acc[mi][si * 2 + ni] = __builtin_amdgcn_mfma_f32_16x16x32_bf16(
                        af[mi][ki], bfr[ni][ki], acc[mi][si * 2 + ni], 0, 0, 0);
    }

    float rmx[2][4], rinv[2][4];
    #pragma unroll
    for (int mi = 0; mi < 2; ++mi)
        #pragma unroll
        for (int r = 0; r < 4; ++r) {
            float mx = acc[mi][0][r];
            #pragma unroll
            for (int j = 1; j < 16; ++j) mx = fmaxf(mx, acc[mi][j][r]);
            #pragma unroll
            for (int off = 1; off < 16; off <<= 1) mx = fmaxf(mx, __shfl_xor(mx, off, 64));
            rmx[mi][r] = mx;
        }
    if (col == 0) {
        #pragma unroll
        for (int mi = 0; mi < 2; ++mi)
            #pragma unroll
            for (int r = 0; r < 4; ++r)
                red[0][w][mi * 16 + quad * 4 + r] = rmx[mi][r];
    }
    __syncthreads();
    #pragma unroll
    for (int mi = 0; mi < 2; ++mi)
        #pragma unroll
        for (int r = 0; r < 4; ++r) {
            int row = mi * 16 + quad * 4 + r;
            rmx[mi][r] = fmaxf(fmaxf(red[0][0][row], red[0][1][row]),
                               fmaxf(red[0][2][row], red[0][3][row]));
        }
    #pragma unroll
    for (int mi = 0; mi < 2; ++mi)
        #pragma unroll
        for (int r = 0; r < 4; ++r) {
            float s = 0.f;
            #pragma unroll
            for (int j = 0; j < 16; ++j) {
                acc[mi][j][r] = __expf(acc[mi][j][r] - rmx[mi][r]);
                s += acc[mi][j][r];
            }
            #pragma unroll
            for (int off = 1; off < 16; off <<= 1) s += __shfl_xor(s, off, 64);
            rinv[mi][r] = s;
        }
    if (col == 0) {
        #pragma unroll
        for (int mi = 0; mi < 2; ++mi)
            #pragma unroll
            for (int r = 0; r < 4; ++r)
                red[1][w][mi * 16 + quad * 4 + r] = rinv[mi][r];
    }
    __syncthreads();
    #pragma unroll
    for (int mi = 0; mi < 2; ++mi)
        #pragma unroll
        for (int r = 0; r < 4; ++r) {
            int row = mi * 16 + quad * 4 + r;
            float s4 = red[1][0][row] + red[1][1][row] + red[1][2][row] + red[1][3][row];
            rinv[mi][r] = 1.0f / s4;
        }

    bf16* dst = attn + ((long)(zb * 8 + zh)) * 1048576 + (long)t0 * 1024;
    #pragma unroll
    for (int mi = 0; mi < 2; ++mi) {
        __syncthreads();
        #pragma unroll
        for (int j = 0; j < 16; ++j) {
            int colb = (j >> 1) * 128 + w * 32 + (j & 1) * 16 + col;
            #pragma unroll
            for (int r = 0; r < 4; ++r) {
                int rowh = quad * 4 + r;
                Sbuf[rowh * PAD + colb] = __float2bfloat16(acc[mi][j][r] * rinv[mi][r]);
            }
        }
        __syncthreads();
        #pragma unroll
        for (int i = 0; i < 8; ++i) {
            int c = i * 256 + tid;             // 16 rows x 128 chunks
            int rowh = c >> 7, jj = c & 127;
            bf16x8 vv = *(const bf16x8*)(Sbuf + rowh * PAD + jj * 8);
            *(bf16x8*)(dst + (long)(mi * 16 + rowh) * 1024 + jj * 8) = vv;
        }
    }
}

// x (B,C,T) f32 -> xt (B,T,C) bf16, 32x32 LDS tiles
__global__ __launch_bounds__(256)
void transpose_cast_x(const float* __restrict__ x, bf16* __restrict__ xt)
{
    __shared__ float tile[32][33];
    int b = blockIdx.z;
    int c0 = blockIdx.y * 32, t0 = blockIdx.x * 32;
    int tx = threadIdx.x & 31, ty = threadIdx.x >> 5;  // ty 0..7
    const float* xb = x + (long)b * 1024 * 1024;
    #pragma unroll
    for (int i = 0; i < 4; ++i) {
        int c = ty + i * 8;
        tile[c][tx] = xb[(long)(c0 + c) * 1024 + t0 + tx];
    }
    __syncthreads();
    bf16* xtb = xt + (long)b * 1024 * 1024;
    #pragma unroll
    for (int i = 0; i < 4; ++i) {
        int t = ty + i * 8;
        xtb[(long)(t0 + t) * 1024 + c0 + tx] = __float2bfloat16(tile[tx][t]);
    }
}

__global__ __launch_bounds__(256)
void cast_f2b(const float* __restrict__ in, bf16* __restrict__ out, long n)
{
    long i = (long)blockIdx.x * 256 + threadIdx.x;
    long stride = (long)gridDim.x * 256;
    for (; i < n; i += stride) out[i] = __float2bfloat16(in[i]);
}

// Build stacked qk weight (2048 x 1024 bf16)
__global__ __launch_bounds__(256)
void build_wqk(const float* __restrict__ Wq, const float* __restrict__ Wk,
               const float* __restrict__ bq, const float* __restrict__ bk,
               bf16* __restrict__ Wqk, float* __restrict__ biasqk)
{
    long i = (long)blockIdx.x * 256 + threadIdx.x;   // 2048*1024 total
    long r = i >> 10, c = i & 1023;
    long h = r >> 8, rr = r & 255;
    float v = (rr < 128) ? Wq[(h * 128 + rr) * 1024 + c]
                         : Wk[(h * 128 + (rr - 128)) * 1024 + c];
    Wqk[i] = __float2bfloat16(v);
    if (c == 0)
        biasqk[r] = (rr < 128) ? bq[h * 128 + rr] : bk[h * 128 + rr - 128];
}

extern "C" void kernel_launch(void* const* d_in, const int* in_sizes, int n_in,
                              void* d_out, int out_size, void* d_ws, size_t ws_size,
                              hipStream_t stream)
{
    const float* x     = (const float*)d_in[0];
    const float* Wq    = (const float*)d_in[1];
    const float* bq    = (const float*)d_in[2];
    const float* Wk    = (const float*)d_in[3];
    const float* bk    = (const float*)d_in[4];
    const float* Wv    = (const float*)d_in[5];
    const float* bv    = (const float*)d_in[6];
    const float* gamma = (const float*)d_in[7];
    const float* W1    = (const float*)d_in[8];
    const float* b1    = (const float*)d_in[9];
    const float* W2    = (const float*)d_in[10];
    const float* b2    = (const float*)d_in[11];
    float* out = (float*)d_out;

    // chunk=4, two passes. Workspace (256 MiB exactly), MiB offsets:
    // [0,16)    xt            (live whole run)
    // [16,32)   Wvb           (live through pass-2 v-proj)
    // [32,96)   vbuf (pass)   — Wqk@[32,36) + bqk@[36,..) overlay, dead before pass-1 v
    // [96,160)  attb (pass)   — post-O per pass: W1b@96, W2b@96+0.5M, y1c@[97,105)
    // [160,224) ot   (pass)
    // [224,256) qkt           (live through pass-2 attn_fused)
    char* base = (char*)d_ws;
    const long MB = 1048576;
    bf16*  xt   = (bf16*)(base);
    bf16*  Wvb  = (bf16*)(base + 16 * MB);
    bf16*  vbuf = (bf16*)(base + 32 * MB);
    bf16*  Wqk  = (bf16*)(base + 32 * MB);          // dead after qk-proj
    float* bqk  = (float*)(base + 36 * MB);         // dead after qk-proj
    bf16*  attb = (bf16*)(base + 96 * MB);
    bf16*  W1b  = (bf16*)(base + 96 * MB);          // post-O overlay, re-cast per pass
    bf16*  W2b  = (bf16*)(base + 96 * MB + 524288);
    bf16*  y1c  = (bf16*)(base + 97 * MB);          // 8 MiB per pass
    bf16*  ot   = (bf16*)(base + 160 * MB);
    bf16*  qkt  = (bf16*)(base + 224 * MB);

    dim3 blk(256);
    transpose_cast_x<<<dim3(32, 32, 8), blk, 0, stream>>>(x, xt);
    build_wqk<<<8192, blk, 0, stream>>>(Wq, Wk, bq, bk, Wqk, bqk);
    cast_f2b<<<4096, blk, 0, stream>>>(Wv, Wvb, 8192ll * 1024);

    const long M1 = 1048576, M2 = 2097152, M8 = 8388608;

    // qk_t: M=8192 (b,t), N=2048 (h*256+o), K=1024 — full batch
    gemm_nt<1, 64, false><<<dim3(16, 64, 1), blk, 0, stream>>>(
        xt, 1024, 0, 0, Wqk, 1024, 0, 0, qkt, 2048, 0, 0, 1024,
        bqk, 0, nullptr, nullptr, 0, nullptr);

    for (int q = 0; q < 2; ++q) {
        const long b0 = (long)q * 4;
        const bf16* xtq = xt + b0 * M1;
        // v(zb,zh;c,s) = Wv[zh](c,ci) . xt(b0+zb;s,ci)^T + bv[zh,c]
        // 32 slices -> 2048 blocks (8/CU); zh == blockIdx.x%8 pins Wv[zh] per XCD
        gemm_nt<0, 64, true><<<dim3(32, 8, 8), blk, 0, stream>>>(
            Wvb, 1024, 0, M1, xtq, 1024, M1, 0, vbuf, 1024, M8, M1, 1024,
            bv, 1024, nullptr, nullptr, 0, nullptr);
        // fused E + softmax -> attb bf16 (1024 blocks)
        attn_fused<<<dim3(32, 32, 1), blk, 0, stream>>>(
            qkt + b0 * M2, attb);
        // heads_t(zb,zh;t,c) = gamma[zh]*(attn(t,s).v(c,s)^T) + xt(b0+zb;t,c)
        gemm_nt<3, 64, true><<<dim3(32, 8, 8), blk, 0, stream>>>(
            attb, 1024, M8, M1, vbuf, 1024, M8, M1,
            ot, 1024, M8, M1, 1024,
            nullptr, 0, gamma, xtq, 1024, nullptr);
        // attb dead: cast FC weights into its region (re-done each pass)
        cast_f2b<<<512, blk, 0, stream>>>(W1, W1b, 128 * 1024);
        cast_f2b<<<64, blk, 0, stream>>>(W2, W2b, 128 * 128);
        // y1c = relu(ot . W1^T + b1): M=32768, N=128, K=1024 (256 blocks, ot LLC-warm)
        gemm_nt<4, 64, false><<<dim3(1, 256, 1), blk, 0, stream>>>(
            ot, 1024, 0, 0, W1b, 1024, 0, 0, y1c, 128, 0, 0, 1024,
            b1, 0, nullptr, nullptr, 0, nullptr);
        // out = relu(y1c . W2^T + b2) scattered + x (pass-local rows)
        gemm_nt<5, 128, false><<<dim3(1, 256, 1), blk, 0, stream>>>(
            y1c, 128, 0, 0, W2b, 128, 0, 0, out + b0 * M1, 0, 0, 0, 128,
            b2, 0, nullptr, nullptr, 0, x + b0 * M1);
    }
}

// Round 4
// 678.414 us; speedup vs baseline: 1.0624x; 1.0624x over previous
//
#include <hip/hip_runtime.h>
#include <hip/hip_bf16.h>

typedef __hip_bfloat16 bf16;
typedef __attribute__((ext_vector_type(8))) __bf16 bf16x8;
typedef __attribute__((ext_vector_type(4))) float f32x4;

#define BM 128
#define BN 128

typedef const __attribute__((address_space(1))) void gvoid;
typedef __attribute__((address_space(3))) void lvoid;

// NT GEMM: C[m,n] = sum_k A[m,k] * B[n,k]   (both row-major, K contiguous)
// z decomposes as zb = z>>3 (local batch), zh = z&7 (head).
// SLICEX: slice index lives in blockIdx.x (XCD-pinned: zh == XCD id), n-tile in blockIdx.z.
// MODE 0: C bf16 = acc + bias[zh*sBiasZ + m]                 (v proj)
// MODE 1: C bf16 = acc + bias[n]                             (qk proj)
// MODE 3: C bf16 = gamma[zh]*acc + xt[zb*1M + m*ldxt + n]    (o -> heads_t)
// MODE 4: C bf16 = relu(acc + bias[n])                       (fc1)
// MODE 5: out f32 scatter + residual (m local row; Cv/xf pre-offset per pass)
//
// R4: K-loop-invariant addressing hoisted out of the hot loop.
//  - staging addrs: 2*NSLOT per-lane pointers, += TBK elements per K-step
//  - LDS fragment offsets: NX*4 A + NX*4 B ints computed once
//  - epilogue: incremental row pointers; bias[n] preloaded per ni
template<int MODE, int TBK, bool SLICEX>
__global__ __launch_bounds__(256)
void gemm_nt(const bf16* __restrict__ A, long lda, long sAb, long sAh,
             const bf16* __restrict__ B, long ldb, long sBb, long sBh,
             void* __restrict__ Cv, long ldc, long sCb, long sCh,
             int K,
             const float* __restrict__ bias, long sBiasZ,
             const float* __restrict__ gamma,
             const bf16* __restrict__ xt, long ldxt,
             const float* __restrict__ xf)
{
    __shared__ bf16 As[BM * TBK];
    __shared__ bf16 Bs[BN * TBK];
    const int bxt = SLICEX ? blockIdx.z : blockIdx.x;   // n-tile
    const int z   = SLICEX ? blockIdx.x : blockIdx.z;   // slice
    const int zb = z >> 3, zh = z & 7;
    const bf16* Ab = A + (long)zb * sAb + (long)zh * sAh + (long)blockIdx.y * BM * lda;
    const bf16* Bb = B + (long)zb * sBb + (long)zh * sBh + (long)bxt * BN * ldb;
    const int tid  = threadIdx.x;
    const int wave = tid >> 6, lane = tid & 63;
    const int col  = lane & 15, quad = lane >> 4;
    const int wm = (wave & 1) * 64, wn = (wave >> 1) * 64;
    constexpr int CPR = TBK / 8;            // 16B chunks per row
    constexpr int NSLOT = TBK / 16;         // staging slots per operand
    constexpr int NX = TBK / 32;            // kk iterations

    // --- hoisted per-lane staging addresses (K-invariant shape, +TBK/step) ---
    const bf16* aAddr[NSLOT];
    const bf16* bAddr[NSLOT];
    #pragma unroll
    for (int i = 0; i < NSLOT; ++i) {
        int cbase = i * 256 + wave * 64;     // wave-uniform chunk base
        int c = cbase + lane;                // chunk id
        int m = c / CPR;                     // tile row
        int j = c % CPR;                     // chunk slot in row
        int kch = ((j ^ (m & 7)) << 3);      // swizzled k offset (elements)
        aAddr[i] = Ab + (long)m * lda + kch;
        bAddr[i] = Bb + (long)m * ldb + kch;
    }

    // --- hoisted LDS fragment byte-offsets (fully K-invariant) ---
    int offA[NX][4], offB[NX][4];
    #pragma unroll
    for (int x = 0; x < NX; ++x) {
        int kq = x * 4 + quad;               // (kk>>3)+quad with kk = x*32
        #pragma unroll
        for (int mi = 0; mi < 4; ++mi) {
            int m = wm + mi * 16 + col;
            offA[x][mi] = m * TBK + ((kq ^ (m & 7)) << 3);
            int n = wn + mi * 16 + col;
            offB[x][mi] = n * TBK + ((kq ^ (n & 7)) << 3);
        }
    }

    f32x4 acc[4][4] = {};

    for (int k0 = 0; k0 < K; k0 += TBK) {
        __syncthreads();
        #pragma unroll
        for (int i = 0; i < NSLOT; ++i) {
            int cbase = i * 256 + wave * 64;
            __builtin_amdgcn_global_load_lds(
                (gvoid*)aAddr[i], (lvoid*)(As + cbase * 8), 16, 0, 0);
            __builtin_amdgcn_global_load_lds(
                (gvoid*)bAddr[i], (lvoid*)(Bs + cbase * 8), 16, 0, 0);
            aAddr[i] += TBK;
            bAddr[i] += TBK;
        }
        __syncthreads();
        #pragma unroll
        for (int x = 0; x < NX; ++x) {
            bf16x8 af[4], bfr[4];
            #pragma unroll
            for (int mi = 0; mi < 4; ++mi)
                af[mi] = *(const bf16x8*)(As + offA[x][mi]);
            #pragma unroll
            for (int ni = 0; ni < 4; ++ni)
                bfr[ni] = *(const bf16x8*)(Bs + offB[x][ni]);
            #pragma unroll
            for (int mi = 0; mi < 4; ++mi)
                #pragma unroll
                for (int ni = 0; ni < 4; ++ni)
                    acc[mi][ni] = __builtin_amdgcn_mfma_f32_16x16x32_bf16(
                        af[mi], bfr[ni], acc[mi][ni], 0, 0, 0);
        }
    }

    const long m0 = (long)blockIdx.y * BM + wm;
    const long n0 = (long)bxt * BN + wn;
    float g = 0.f;
    if (MODE == 3) g = gamma[zh];

    // bias[n] is per-ni constant for MODE 1/4/5: preload
    float bn[4];
    if constexpr (MODE == 1 || MODE == 4 || MODE == 5) {
        #pragma unroll
        for (int ni = 0; ni < 4; ++ni)
            bn[ni] = bias[n0 + ni * 16 + col];
    }

    #pragma unroll
    for (int mi = 0; mi < 4; ++mi) {
        #pragma unroll
        for (int ni = 0; ni < 4; ++ni) {
            long mb = m0 + mi * 16 + quad * 4;
            long n  = n0 + ni * 16 + col;
            if constexpr (MODE == 0) {
                bf16* cp = (bf16*)Cv + (long)zb * sCb + (long)zh * sCh + mb * ldc + n;
                const float* bp = bias + zh * sBiasZ + mb;
                #pragma unroll
                for (int r = 0; r < 4; ++r) {
                    float v = acc[mi][ni][r] + bp[r];
                    *cp = __float2bfloat16(v);
                    cp += ldc;
                }
            } else if constexpr (MODE == 1) {
                bf16* cp = (bf16*)Cv + mb * ldc + n;
                #pragma unroll
                for (int r = 0; r < 4; ++r) {
                    float v = acc[mi][ni][r] + bn[ni];
                    *cp = __float2bfloat16(v);
                    cp += ldc;
                }
            } else if constexpr (MODE == 3) {
                bf16* cp = (bf16*)Cv + (long)zb * sCb + (long)zh * sCh + mb * ldc + n;
                const bf16* xp = xt + (long)zb * 1048576 + mb * ldxt + n;
                #pragma unroll
                for (int r = 0; r < 4; ++r) {
                    float xv = __bfloat162float(*xp);
                    *cp = __float2bfloat16(g * acc[mi][ni][r] + xv);
                    cp += ldc;
                    xp += ldxt;
                }
            } else if constexpr (MODE == 4) {
                bf16* cp = (bf16*)Cv + mb * ldc + n;
                #pragma unroll
                for (int r = 0; r < 4; ++r) {
                    float v = acc[mi][ni][r] + bn[ni];
                    v = v > 0.f ? v : 0.f;
                    *cp = __float2bfloat16(v);
                    cp += ldc;
                }
            } else {  // MODE 5: m local = bb*8192 + h*1024 + t (bb within pass)
                #pragma unroll
                for (int r = 0; r < 4; ++r) {
                    long m = mb + r;
                    float v = acc[mi][ni][r] + bn[ni];
                    v = v > 0.f ? v : 0.f;
                    long bb = m >> 13, h = (m >> 10) & 7, t = m & 1023;
                    long oi = bb * 1048576 + (n * 8 + h) * 1024 + t;
                    ((float*)Cv)[oi] = v + xf[oi];
                }
            }
        }
    }
}

// Fused energy + softmax. Grid: (slices, T/32). Block 256 (4 waves).
__global__ __launch_bounds__(256, 2)
void attn_fused(const bf16* __restrict__ qk, bf16* __restrict__ attn)
{
    constexpr int PAD = 1032;
    __shared__ __align__(16) char smraw[40960];   // phase A: Q 8K + K 32K; phase B: Sbuf 33024B
    __shared__ float red[2][4][32];
    bf16* Qs = (bf16*)smraw;                  // [32][128]
    bf16* Ks = (bf16*)(smraw + 8192);         // [128][128]
    bf16* Sbuf = (bf16*)smraw;                // [16][PAD]

    const int z = blockIdx.x;
    const int zb = z >> 3, zh = z & 7;
    const int t0 = blockIdx.y * 32;
    const int tid = threadIdx.x, w = tid >> 6, lane = tid & 63;
    const int col = lane & 15, quad = lane >> 4;

    const bf16* Qbase = qk + ((long)zb * 1024 + t0) * 2048 + zh * 256;
    const bf16* Kbase = qk + (long)zb * 1024 * 2048 + zh * 256 + 128;

    #pragma unroll
    for (int i = 0; i < 2; ++i) {
        int cbase = i * 256 + w * 64;
        int c = cbase + lane;
        int m = c >> 4, j = c & 15;
        __builtin_amdgcn_global_load_lds(
            (gvoid*)(Qbase + (long)m * 2048 + ((j ^ (m & 7)) << 3)),
            (lvoid*)(Qs + cbase * 8), 16, 0, 0);
    }
    __syncthreads();
    bf16x8 af[2][4];
    #pragma unroll
    for (int mi = 0; mi < 2; ++mi) {
        int m = mi * 16 + col;
        #pragma unroll
        for (int ki = 0; ki < 4; ++ki)
            af[mi][ki] = *(const bf16x8*)(Qs + m * 128 + ((((ki << 2) + quad) ^ (m & 7)) << 3));
    }

    f32x4 acc[2][16] = {};
    #pragma unroll
    for (int si = 0; si < 8; ++si) {
        __syncthreads();
        const bf16* Kb = Kbase + (long)si * 128 * 2048;
        #pragma unroll
        for (int i = 0; i < 8; ++i) {
            int cbase = i * 256 + w * 64;
            int c = cbase + lane;
            int m = c >> 4, j = c & 15;
            __builtin_amdgcn_global_load_lds(
                (gvoid*)(Kb + (long)m * 2048 + ((j ^ (m & 7)) << 3)),
                (lvoid*)(Ks + cbase * 8), 16, 0, 0);
        }
        __syncthreads();
        bf16x8 bfr[2][4];
        #pragma unroll
        for (int ni = 0; ni < 2; ++ni) {
            int n = w * 32 + ni * 16 + col;
            #pragma unroll
            for (int ki = 0; ki < 4; ++ki)
                bfr[ni][ki] = *(const bf16x8*)(Ks + n * 128 + ((((ki << 2) + quad) ^ (n & 7)) << 3));
        }
        #pragma unroll
        for (int ki = 0; ki < 4; ++ki)
            #pragma unroll
            for (int mi = 0; mi < 2; ++mi)
                #pragma unroll
                for (int ni = 0; ni < 2; ++ni)
                    acc[mi][si * 2 + ni] = __builtin_amdgcn_mfma_f32_16x16x32_bf16(
                        af[mi][ki], bfr[ni][ki], acc[mi][si * 2 + ni], 0, 0, 0);
    }

    float rmx[2][4], rinv[2][4];
    #pragma unroll
    for (int mi = 0; mi < 2; ++mi)
        #pragma unroll
        for (int r = 0; r < 4; ++r) {
            float mx = acc[mi][0][r];
            #pragma unroll
            for (int j = 1; j < 16; ++j) mx = fmaxf(mx, acc[mi][j][r]);
            #pragma unroll
            for (int off = 1; off < 16; off <<= 1) mx = fmaxf(mx, __shfl_xor(mx, off, 64));
            rmx[mi][r] = mx;
        }
    if (col == 0) {
        #pragma unroll
        for (int mi = 0; mi < 2; ++mi)
            #pragma unroll
            for (int r = 0; r < 4; ++r)
                red[0][w][mi * 16 + quad * 4 + r] = rmx[mi][r];
    }
    __syncthreads();
    #pragma unroll
    for (int mi = 0; mi < 2; ++mi)
        #pragma unroll
        for (int r = 0; r < 4; ++r) {
            int row = mi * 16 + quad * 4 + r;
            rmx[mi][r] = fmaxf(fmaxf(red[0][0][row], red[0][1][row]),
                               fmaxf(red[0][2][row], red[0][3][row]));
        }
    #pragma unroll
    for (int mi = 0; mi < 2; ++mi)
        #pragma unroll
        for (int r = 0; r < 4; ++r) {
            float s = 0.f;
            #pragma unroll
            for (int j = 0; j < 16; ++j) {
                acc[mi][j][r] = __expf(acc[mi][j][r] - rmx[mi][r]);
                s += acc[mi][j][r];
            }
            #pragma unroll
            for (int off = 1; off < 16; off <<= 1) s += __shfl_xor(s, off, 64);
            rinv[mi][r] = s;
        }
    if (col == 0) {
        #pragma unroll
        for (int mi = 0; mi < 2; ++mi)
            #pragma unroll
            for (int r = 0; r < 4; ++r)
                red[1][w][mi * 16 + quad * 4 + r] = rinv[mi][r];
    }
    __syncthreads();
    #pragma unroll
    for (int mi = 0; mi < 2; ++mi)
        #pragma unroll
        for (int r = 0; r < 4; ++r) {
            int row = mi * 16 + quad * 4 + r;
            float s4 = red[1][0][row] + red[1][1][row] + red[1][2][row] + red[1][3][row];
            rinv[mi][r] = 1.0f / s4;
        }

    bf16* dst = attn + ((long)(zb * 8 + zh)) * 1048576 + (long)t0 * 1024;
    #pragma unroll
    for (int mi = 0; mi < 2; ++mi) {
        __syncthreads();
        #pragma unroll
        for (int j = 0; j < 16; ++j) {
            int colb = (j >> 1) * 128 + w * 32 + (j & 1) * 16 + col;
            #pragma unroll
            for (int r = 0; r < 4; ++r) {
                int rowh = quad * 4 + r;
                Sbuf[rowh * PAD + colb] = __float2bfloat16(acc[mi][j][r] * rinv[mi][r]);
            }
        }
        __syncthreads();
        #pragma unroll
        for (int i = 0; i < 8; ++i) {
            int c = i * 256 + tid;             // 16 rows x 128 chunks
            int rowh = c >> 7, jj = c & 127;
            bf16x8 vv = *(const bf16x8*)(Sbuf + rowh * PAD + jj * 8);
            *(bf16x8*)(dst + (long)(mi * 16 + rowh) * 1024 + jj * 8) = vv;
        }
    }
}

// x (B,C,T) f32 -> xt (B,T,C) bf16, 32x32 LDS tiles
__global__ __launch_bounds__(256)
void transpose_cast_x(const float* __restrict__ x, bf16* __restrict__ xt)
{
    __shared__ float tile[32][33];
    int b = blockIdx.z;
    int c0 = blockIdx.y * 32, t0 = blockIdx.x * 32;
    int tx = threadIdx.x & 31, ty = threadIdx.x >> 5;  // ty 0..7
    const float* xb = x + (long)b * 1024 * 1024;
    #pragma unroll
    for (int i = 0; i < 4; ++i) {
        int c = ty + i * 8;
        tile[c][tx] = xb[(long)(c0 + c) * 1024 + t0 + tx];
    }
    __syncthreads();
    bf16* xtb = xt + (long)b * 1024 * 1024;
    #pragma unroll
    for (int i = 0; i < 4; ++i) {
        int t = ty + i * 8;
        xtb[(long)(t0 + t) * 1024 + c0 + tx] = __float2bfloat16(tile[tx][t]);
    }
}

__global__ __launch_bounds__(256)
void cast_f2b(const float* __restrict__ in, bf16* __restrict__ out, long n)
{
    long i = (long)blockIdx.x * 256 + threadIdx.x;
    long stride = (long)gridDim.x * 256;
    for (; i < n; i += stride) out[i] = __float2bfloat16(in[i]);
}

// Build stacked qk weight (2048 x 1024 bf16)
__global__ __launch_bounds__(256)
void build_wqk(const float* __restrict__ Wq, const float* __restrict__ Wk,
               const float* __restrict__ bq, const float* __restrict__ bk,
               bf16* __restrict__ Wqk, float* __restrict__ biasqk)
{
    long i = (long)blockIdx.x * 256 + threadIdx.x;   // 2048*1024 total
    long r = i >> 10, c = i & 1023;
    long h = r >> 8, rr = r & 255;
    float v = (rr < 128) ? Wq[(h * 128 + rr) * 1024 + c]
                         : Wk[(h * 128 + (rr - 128)) * 1024 + c];
    Wqk[i] = __float2bfloat16(v);
    if (c == 0)
        biasqk[r] = (rr < 128) ? bq[h * 128 + rr] : bk[h * 128 + rr - 128];
}

extern "C" void kernel_launch(void* const* d_in, const int* in_sizes, int n_in,
                              void* d_out, int out_size, void* d_ws, size_t ws_size,
                              hipStream_t stream)
{
    const float* x     = (const float*)d_in[0];
    const float* Wq    = (const float*)d_in[1];
    const float* bq    = (const float*)d_in[2];
    const float* Wk    = (const float*)d_in[3];
    const float* bk    = (const float*)d_in[4];
    const float* Wv    = (const float*)d_in[5];
    const float* bv    = (const float*)d_in[6];
    const float* gamma = (const float*)d_in[7];
    const float* W1    = (const float*)d_in[8];
    const float* b1    = (const float*)d_in[9];
    const float* W2    = (const float*)d_in[10];
    const float* b2    = (const float*)d_in[11];
    float* out = (float*)d_out;

    // chunk=4, two passes. Workspace (256 MiB exactly), MiB offsets:
    // [0,16)    xt            (live whole run)
    // [16,32)   Wvb           (live through pass-2 v-proj)
    // [32,96)   vbuf (pass)   — Wqk@[32,36) + bqk@[36,..) overlay, dead before pass-1 v
    // [96,160)  attb (pass)   — post-O per pass: W1b@96, W2b@96+0.5M, y1c@[97,105)
    // [160,224) ot   (pass)
    // [224,256) qkt           (live through pass-2 attn_fused)
    char* base = (char*)d_ws;
    const long MB = 1048576;
    bf16*  xt   = (bf16*)(base);
    bf16*  Wvb  = (bf16*)(base + 16 * MB);
    bf16*  vbuf = (bf16*)(base + 32 * MB);
    bf16*  Wqk  = (bf16*)(base + 32 * MB);          // dead after qk-proj
    float* bqk  = (float*)(base + 36 * MB);         // dead after qk-proj
    bf16*  attb = (bf16*)(base + 96 * MB);
    bf16*  W1b  = (bf16*)(base + 96 * MB);          // post-O overlay, re-cast per pass
    bf16*  W2b  = (bf16*)(base + 96 * MB + 524288);
    bf16*  y1c  = (bf16*)(base + 97 * MB);          // 8 MiB per pass
    bf16*  ot   = (bf16*)(base + 160 * MB);
    bf16*  qkt  = (bf16*)(base + 224 * MB);

    dim3 blk(256);
    transpose_cast_x<<<dim3(32, 32, 8), blk, 0, stream>>>(x, xt);
    build_wqk<<<8192, blk, 0, stream>>>(Wq, Wk, bq, bk, Wqk, bqk);
    cast_f2b<<<4096, blk, 0, stream>>>(Wv, Wvb, 8192ll * 1024);

    const long M1 = 1048576, M2 = 2097152, M8 = 8388608;

    // qk_t: M=8192 (b,t), N=2048 (h*256+o), K=1024 — full batch
    gemm_nt<1, 64, false><<<dim3(16, 64, 1), blk, 0, stream>>>(
        xt, 1024, 0, 0, Wqk, 1024, 0, 0, qkt, 2048, 0, 0, 1024,
        bqk, 0, nullptr, nullptr, 0, nullptr);

    for (int q = 0; q < 2; ++q) {
        const long b0 = (long)q * 4;
        const bf16* xtq = xt + b0 * M1;
        // v(zb,zh;c,s) = Wv[zh](c,ci) . xt(b0+zb;s,ci)^T + bv[zh,c]
        // 32 slices -> 2048 blocks (8/CU); zh == blockIdx.x%8 pins Wv[zh] per XCD
        gemm_nt<0, 64, true><<<dim3(32, 8, 8), blk, 0, stream>>>(
            Wvb, 1024, 0, M1, xtq, 1024, M1, 0, vbuf, 1024, M8, M1, 1024,
            bv, 1024, nullptr, nullptr, 0, nullptr);
        // fused E + softmax -> attb bf16 (1024 blocks)
        attn_fused<<<dim3(32, 32, 1), blk, 0, stream>>>(
            qkt + b0 * M2, attb);
        // heads_t(zb,zh;t,c) = gamma[zh]*(attn(t,s).v(c,s)^T) + xt(b0+zb;t,c)
        gemm_nt<3, 64, true><<<dim3(32, 8, 8), blk, 0, stream>>>(
            attb, 1024, M8, M1, vbuf, 1024, M8, M1,
            ot, 1024, M8, M1, 1024,
            nullptr, 0, gamma, xtq, 1024, nullptr);
        // attb dead: cast FC weights into its region (re-done each pass)
        cast_f2b<<<512, blk, 0, stream>>>(W1, W1b, 128 * 1024);
        cast_f2b<<<64, blk, 0, stream>>>(W2, W2b, 128 * 128);
        // y1c = relu(ot . W1^T + b1): M=32768, N=128, K=1024 (256 blocks, ot LLC-warm)
        gemm_nt<4, 64, false><<<dim3(1, 256, 1), blk, 0, stream>>>(
            ot, 1024, 0, 0, W1b, 1024, 0, 0, y1c, 128, 0, 0, 1024,
            b1, 0, nullptr, nullptr, 0, nullptr);
        // out = relu(y1c . W2^T + b2) scattered + x (pass-local rows)
        gemm_nt<5, 128, false><<<dim3(1, 256, 1), blk, 0, stream>>>(
            y1c, 128, 0, 0, W2b, 128, 0, 0, out + b0 * M1, 0, 0, 0, 128,
            b2, 0, nullptr, nullptr, 0, x + b0 * M1);
    }
}